// Round 1
// baseline (258.159 us; speedup 1.0000x reference)
//
#include <hip/hip_runtime.h>

typedef __bf16 bf16_t;
typedef bf16_t bf16x8 __attribute__((ext_vector_type(8)));
typedef float f32x4 __attribute__((ext_vector_type(4)));
typedef unsigned short u16;

#define MFMA16(a, b, c) __builtin_amdgcn_mfma_f32_16x16x32_bf16((a), (b), (c), 0, 0, 0)

// Model dims (fixed by the reference)
#define BATCH 2
#define SEQ   2048
#define DIM   1024
#define NH    16
#define HD    64
#define ROWS  (BATCH * SEQ)      // 4096
#define QKVN  (3 * DIM)          // 3072

__device__ __forceinline__ u16 f2bf(float f) {
    unsigned u = __float_as_uint(f);
    u += 0x7FFFu + ((u >> 16) & 1u);   // RNE
    return (u16)(u >> 16);
}

// ---------------------------------------------------------------------------
// fp32 -> bf16 conversion of x, w_qkv, w_out
// ---------------------------------------------------------------------------
__global__ __launch_bounds__(256) void cvt_kernel(
    const float* __restrict__ x,  u16* __restrict__ xb,  int nx4,
    const float* __restrict__ w1, u16* __restrict__ w1b, int n14,
    const float* __restrict__ w2, u16* __restrict__ w2b, int n24)
{
    const int total = nx4 + n14 + n24;
    for (int i = blockIdx.x * 256 + threadIdx.x; i < total; i += gridDim.x * 256) {
        const float4* s; ushort4* d; int o;
        if (i < nx4)             { s = (const float4*)x;  d = (ushort4*)xb;  o = i; }
        else if (i < nx4 + n14)  { s = (const float4*)w1; d = (ushort4*)w1b; o = i - nx4; }
        else                     { s = (const float4*)w2; d = (ushort4*)w2b; o = i - nx4 - n14; }
        float4 v = s[o];
        ushort4 r;
        r.x = f2bf(v.x); r.y = f2bf(v.y); r.z = f2bf(v.z); r.w = f2bf(v.w);
        d[o] = r;
    }
}

// ---------------------------------------------------------------------------
// C[M][N] = A[M][K] @ Bt[N][K]^T + bias[N]   (bf16 in, fp32 acc)
// 128x128 tile, BK=64, 4 waves (2x2), 16x16x32 bf16 MFMA, global_load_lds.
// ---------------------------------------------------------------------------
template <bool OUT_F32>
__global__ __launch_bounds__(256) void gemm_bt(
    const u16* __restrict__ A, const u16* __restrict__ Bt,
    const float* __restrict__ bias, void* __restrict__ Cv,
    int M, int N, int K)
{
    __shared__ u16 As[128 * 64];
    __shared__ u16 Bs[128 * 64];

    const int tid  = threadIdx.x;
    const int lane = tid & 63;
    const int wave = tid >> 6;
    const int r16  = lane & 15;
    const int grp  = lane >> 4;

    const int nt  = N >> 7;
    const int nwg = (M >> 7) * nt;
    int v = blockIdx.x;
    if ((nwg & 7) == 0) { const int cpx = nwg >> 3; v = (v & 7) * cpx + (v >> 3); }
    const int tm = v / nt, tn = v - tm * nt;
    const size_t brow = (size_t)tm << 7;
    const size_t bcol = (size_t)tn << 7;

    const int wr = wave >> 1, wc = wave & 1;

    f32x4 acc[4][4];
    const f32x4 fz = {0.f, 0.f, 0.f, 0.f};
    #pragma unroll
    for (int m = 0; m < 4; ++m)
        #pragma unroll
        for (int n = 0; n < 4; ++n) acc[m][n] = fz;

    for (int kt = 0; kt < K; kt += 64) {
        #pragma unroll
        for (int it = 0; it < 4; ++it) {
            const int cbase = (it * 4 + wave) * 64;     // chunk base (wave-uniform)
            const int c   = cbase + lane;               // 16B chunk id
            const int row = c >> 3, cb = c & 7;
            const u16* ga = A  + (brow + row) * (size_t)K + kt + cb * 8;
            const u16* gb = Bt + (bcol + row) * (size_t)K + kt + cb * 8;
            __builtin_amdgcn_global_load_lds(
                (const __attribute__((address_space(1))) void*)ga,
                (__attribute__((address_space(3))) void*)&As[cbase * 8], 16, 0, 0);
            __builtin_amdgcn_global_load_lds(
                (const __attribute__((address_space(1))) void*)gb,
                (__attribute__((address_space(3))) void*)&Bs[cbase * 8], 16, 0, 0);
        }
        __syncthreads();
        #pragma unroll
        for (int ks = 0; ks < 2; ++ks) {
            bf16x8 af[4], bfr[4];
            #pragma unroll
            for (int m = 0; m < 4; ++m)
                af[m] = *(const bf16x8*)&As[(wr * 64 + m * 16 + r16) * 64 + ks * 32 + grp * 8];
            #pragma unroll
            for (int n = 0; n < 4; ++n)
                bfr[n] = *(const bf16x8*)&Bs[(wc * 64 + n * 16 + r16) * 64 + ks * 32 + grp * 8];
            #pragma unroll
            for (int m = 0; m < 4; ++m)
                #pragma unroll
                for (int n = 0; n < 4; ++n)
                    acc[m][n] = MFMA16(af[m], bfr[n], acc[m][n]);
        }
        __syncthreads();
    }

    #pragma unroll
    for (int n = 0; n < 4; ++n) {
        const size_t col = bcol + wc * 64 + n * 16 + r16;
        const float bv = bias[col];
        #pragma unroll
        for (int m = 0; m < 4; ++m) {
            const size_t row0 = brow + wr * 64 + m * 16 + grp * 4;
            #pragma unroll
            for (int i = 0; i < 4; ++i) {
                const float val = acc[m][n][i] + bv;
                if constexpr (OUT_F32)
                    ((float*)Cv)[(row0 + i) * (size_t)N + col] = val;
                else
                    ((u16*)Cv)[(row0 + i) * (size_t)N + col] = f2bf(val);
            }
        }
    }
}

// ---------------------------------------------------------------------------
// Flash attention: one WG = 64 Q rows of one (b,h); 4 waves x 16 rows.
// KV blocks of 64 keys. K frags direct from global (L2). V staged transposed
// in LDS. P transposed through wave-private LDS for the PV MFMA.
// ---------------------------------------------------------------------------
__global__ __launch_bounds__(256) void attn_kernel(
    const u16* __restrict__ qkv, u16* __restrict__ attb)
{
    __shared__ u16 vt[64 * 72];          // V^T: [d][key], padded stride 72
    __shared__ u16 plds[4][16 * 72];     // per-wave P: [qrow][key]

    const int tid  = threadIdx.x;
    const int lane = tid & 63;
    const int wave = tid >> 6;
    const int r16  = lane & 15;
    const int grp  = lane >> 4;

    int v = (int)blockIdx.x;
    v = (v & 7) * 128 + (v >> 3);        // XCD swizzle: heads grouped per XCD
    const int bh = v >> 5, qb = v & 31;
    const int b  = bh >> 4, h = bh & 15;
    const int bS = b * SEQ;
    const int qbase = qb * 64 + wave * 16;

    // Q fragments (A-operand): row = r16, k = grp*8 + j (+32)
    const u16* qrow = qkv + (size_t)(bS + qbase + r16) * QKVN + h * HD + grp * 8;
    const bf16x8 qf0 = *(const bf16x8*)qrow;
    const bf16x8 qf1 = *(const bf16x8*)(qrow + 32);

    const f32x4 fz = {0.f, 0.f, 0.f, 0.f};
    f32x4 o[4]; 
    #pragma unroll
    for (int dt = 0; dt < 4; ++dt) o[dt] = fz;
    float mrun[4] = {-1e30f, -1e30f, -1e30f, -1e30f};
    float lrun[4] = {0.f, 0.f, 0.f, 0.f};

    const u16* kbase_p = qkv + (size_t)bS * QKVN + DIM + h * HD;
    const u16* vbase_p = qkv + (size_t)bS * QKVN + 2 * DIM + h * HD;
    u16* pl = plds[wave];

    for (int kb = 0; kb < SEQ / 64; ++kb) {
        __syncthreads();                      // protect vt reads of prev iter
        #pragma unroll
        for (int r = 0; r < 2; ++r) {
            const int loc = (tid >> 3) + r * 32;   // key within block
            const int d0  = (tid & 7) * 8;
            const u16* vp = vbase_p + (size_t)(kb * 64 + loc) * QKVN + d0;
            union { uint4 u; u16 s[8]; } uu;
            uu.u = *(const uint4*)vp;
            #pragma unroll
            for (int j = 0; j < 8; ++j) vt[(d0 + j) * 72 + loc] = uu.s[j];
        }
        __syncthreads();

        // QK^T: scores [16 q][64 keys], C-layout per col-tile
        f32x4 sc[4];
        #pragma unroll
        for (int ct = 0; ct < 4; ++ct) {
            const u16* kp = kbase_p + (size_t)(kb * 64 + ct * 16 + r16) * QKVN + grp * 8;
            const bf16x8 k0 = *(const bf16x8*)kp;
            const bf16x8 k1 = *(const bf16x8*)(kp + 32);
            f32x4 z = fz;
            z = MFMA16(qf0, k0, z);
            z = MFMA16(qf1, k1, z);
            sc[ct] = z * 0.125f;              // 1/sqrt(64)
        }

        // online softmax (rows = grp*4+i, reduce over 16 col-lanes)
        #pragma unroll
        for (int i = 0; i < 4; ++i) {
            float tmax = fmaxf(fmaxf(sc[0][i], sc[1][i]), fmaxf(sc[2][i], sc[3][i]));
            #pragma unroll
            for (int msk = 1; msk < 16; msk <<= 1)
                tmax = fmaxf(tmax, __shfl_xor(tmax, msk, 64));
            const float mnew = fmaxf(mrun[i], tmax);
            const float fac  = __expf(mrun[i] - mnew);
            mrun[i] = mnew;
            const float p0 = __expf(sc[0][i] - mnew);
            const float p1 = __expf(sc[1][i] - mnew);
            const float p2 = __expf(sc[2][i] - mnew);
            const float p3 = __expf(sc[3][i] - mnew);
            float ps = p0 + p1 + p2 + p3;
            #pragma unroll
            for (int msk = 1; msk < 16; msk <<= 1)
                ps += __shfl_xor(ps, msk, 64);
            lrun[i] = lrun[i] * fac + ps;
            o[0][i] *= fac; o[1][i] *= fac; o[2][i] *= fac; o[3][i] *= fac;
            const int prow = (grp * 4 + i) * 72 + r16;
            pl[prow]      = f2bf(p0);
            pl[prow + 16] = f2bf(p1);
            pl[prow + 32] = f2bf(p2);
            pl[prow + 48] = f2bf(p3);
        }

        // PV: A = P[16 q][64 k], B = V[64 k][64 d] (from V^T LDS)
        const bf16x8 pa0 = *(const bf16x8*)&pl[r16 * 72 + grp * 8];
        const bf16x8 pa1 = *(const bf16x8*)&pl[r16 * 72 + 32 + grp * 8];
        #pragma unroll
        for (int dt = 0; dt < 4; ++dt) {
            const bf16x8 v0 = *(const bf16x8*)&vt[(dt * 16 + r16) * 72 + grp * 8];
            const bf16x8 v1 = *(const bf16x8*)&vt[(dt * 16 + r16) * 72 + 32 + grp * 8];
            o[dt] = MFMA16(pa0, v0, o[dt]);
            o[dt] = MFMA16(pa1, v1, o[dt]);
        }
    }

    #pragma unroll
    for (int i = 0; i < 4; ++i) {
        const float inv = 1.0f / lrun[i];
        u16* op = attb + (size_t)(bS + qbase + grp * 4 + i) * DIM + h * HD + r16;
        #pragma unroll
        for (int dt = 0; dt < 4; ++dt) op[dt * 16] = f2bf(o[dt][i] * inv);
    }
}

// ---------------------------------------------------------------------------
extern "C" void kernel_launch(void* const* d_in, const int* in_sizes, int n_in,
                              void* d_out, int out_size, void* d_ws, size_t ws_size,
                              hipStream_t stream)
{
    const float* x     = (const float*)d_in[0];
    const float* w_qkv = (const float*)d_in[1];
    const float* b_qkv = (const float*)d_in[2];
    const float* w_out = (const float*)d_in[3];
    const float* b_out = (const float*)d_in[4];
    float* out = (float*)d_out;

    // workspace layout (ushort elements); total 48 MiB
    u16* ws   = (u16*)d_ws;
    u16* XB   = ws;                  // x bf16        [4096][1024]
    u16* WQB  = ws + 4194304;        // w_qkv bf16    [3072][1024]
    u16* WOB  = ws + 7340032;        // w_out bf16    [1024][1024]
    u16* QKVB = ws + 8388608;        // qkv bf16      [4096][3072]
    u16* ATTB = ws + 20971520;       // attn out bf16 [4096][1024]

    cvt_kernel<<<2048, 256, 0, stream>>>(x, XB, (ROWS * DIM) / 4,
                                         w_qkv, WQB, (QKVN * DIM) / 4,
                                         w_out, WOB, (DIM * DIM) / 4);

    gemm_bt<false><<<(ROWS / 128) * (QKVN / 128), 256, 0, stream>>>(
        XB, WQB, b_qkv, (void*)QKVB, ROWS, QKVN, DIM);

    attn_kernel<<<BATCH * NH * (SEQ / 64), 256, 0, stream>>>(QKVB, ATTB);

    gemm_bt<true><<<(ROWS / 128) * (DIM / 128), 256, 0, stream>>>(
        ATTB, WOB, b_out, (void*)out, ROWS, DIM, DIM);
}